// Round 7
// baseline (278.601 us; speedup 1.0000x reference)
//
#include <hip/hip_runtime.h>

// Problem constants (B=8, N=256, DIN=DOUT=EIN=EOUT=64)
#define BN   2048      // B*N
#define NN   256       // N
#define CH   64        // channel dims

typedef __attribute__((ext_vector_type(8))) short short8;   // 8 bf16
typedef __attribute__((ext_vector_type(4))) float fv4;

// fp32 -> bf16 bits, round-to-nearest-even (We prologue only)
static __device__ inline short f2bf(float f) {
  unsigned u = __float_as_uint(f);
  u += 0x7FFF + ((u >> 16) & 1);
  return (short)(u >> 16);
}

// 8 fp32 -> short8 bf16 via packed cvt (RNE), 4 instrs
static __device__ inline short8 cvt_frag(fv4 a, fv4 b) {
  union { short8 s; unsigned u[4]; } r;
  asm("v_cvt_pk_bf16_f32 %0, %1, %2" : "=v"(r.u[0]) : "v"(a[0]), "v"(a[1]));
  asm("v_cvt_pk_bf16_f32 %0, %1, %2" : "=v"(r.u[1]) : "v"(a[2]), "v"(a[3]));
  asm("v_cvt_pk_bf16_f32 %0, %1, %2" : "=v"(r.u[2]) : "v"(b[0]), "v"(b[1]));
  asm("v_cvt_pk_bf16_f32 %0, %1, %2" : "=v"(r.u[3]) : "v"(b[2]), "v"(b[3]));
  return r.s;
}

// ---------------------------------------------------------------------------
// Kernel 1: node_x = emb_node@Wn + bn (fp32), rsx = relu(emb_node@Wsn + bsn).
// ---------------------------------------------------------------------------
__global__ __launch_bounds__(256) void node_kernel(
    const float* __restrict__ emb_node, const float* __restrict__ Wn,
    const float* __restrict__ bn, const float* __restrict__ Wsn,
    const float* __restrict__ bsn, float* __restrict__ node_x,
    float* __restrict__ rsx) {
  __shared__ float s_emb[4][CH];
  __shared__ float s_Wn[CH * CH];   // 16 KB
  __shared__ float s_Ws[CH * CH];   // 16 KB
  const int tid = threadIdx.x;
  const int r = tid >> 6;
  const int c = tid & 63;
  const int row = blockIdx.x * 4 + r;
#pragma unroll
  for (int i = 0; i < 4; ++i) {
    *(fv4*)&s_Wn[(i * 256 + tid) * 4] = *(const fv4*)&Wn[(i * 256 + tid) * 4];
    *(fv4*)&s_Ws[(i * 256 + tid) * 4] = *(const fv4*)&Wsn[(i * 256 + tid) * 4];
  }
  s_emb[r][c] = emb_node[row * CH + c];
  __syncthreads();
  float a1 = bn[c], a2 = bsn[c];
#pragma unroll
  for (int k = 0; k < CH; ++k) {
    const float e = s_emb[r][k];          // wave-uniform broadcast
    a1 = fmaf(e, s_Wn[k * CH + c], a1);
    a2 = fmaf(e, s_Ws[k * CH + c], a2);
  }
  node_x[row * CH + c] = a1;
  rsx[row * CH + c] = fmaxf(a2, 0.0f);
}

// ---------------------------------------------------------------------------
// Kernel 2, round 7: fully wave-independent, asm-pinned depth-4 pipeline.
//   NO LDS, NO barriers. Wave w owns cols [16w,16w+16) x all 256 rows,
//   16 tiles of 16 rows. Swapped MFMA (r6-verified): D = mfma(We, emb):
//   lane (quad,l15) -> row j = t*16+l15, cols cq = 16w+4q..+3.
//   ALL global loads + the edge_out store are asm volatile (compiler cannot
//   sink/collapse them -- the r2/r5 failure mode), with exact counted
//   s_waitcnt vmcnt(N) per tile and sched_barrier(0) after each wait
//   (rule 18: consumers otherwise hoist past inline-asm waitcnt).
//   Per tile: 4 emb dwordx4 + 1 nx dwordx4 + 1 A dword, 1 store dwordx4.
//   Depth 4 -> 24 loads in flight per wave, 16 independent waves/CU.
// ---------------------------------------------------------------------------
__global__ __launch_bounds__(256, 4) void edge_mfma_kernel(
    const float* __restrict__ A, const float* __restrict__ emb_edge,
    const float* __restrict__ We, const float* __restrict__ be,
    const float* __restrict__ node_x, const float* __restrict__ rsx,
    float* __restrict__ node_out, float* __restrict__ edge_out) {
  const int bi   = blockIdx.x;         // b*N + i
  const int b    = bi >> 8;
  const int tid  = threadIdx.x;
  const int lane = tid & 63;
  const int wave = tid >> 6;           // 0..3 -> col tile [16w,16w+16)
  const int l15  = lane & 15;
  const int quad = lane >> 4;
  const int cq   = wave * 16 + quad * 4;   // first of this lane's 4 cols

  const float* __restrict__ ee = emb_edge + (size_t)bi * NN * CH;
  float*       __restrict__ eo = edge_out + (size_t)bi * NN * CH;
  const float* __restrict__ nxp = node_x + (size_t)b * NN * CH;
  const float* __restrict__ Ar = A + (size_t)bi * NN;

  // We fragments (arg0/A-operand of swapped MFMA): A[m=l15][k=quad*8+j]
  short8 wfrag[2];
#pragma unroll
  for (int h = 0; h < 2; ++h)
#pragma unroll
    for (int j = 0; j < 8; ++j)
      wfrag[h][j] = f2bf(We[(h * 32 + quad * 8 + j) * CH + wave * 16 + l15]);
  const fv4 biasv = *(const fv4*)&be[cq];    // cols cq..cq+3 (16B aligned)

  // per-lane byte voffsets (tile stride: emb/nx/eo 4096, A 64)
  const int voe = l15 * 256 + quad * 32;               // emb row l15, k=quad*8
  const int vno = l15 * 256 + wave * 64 + quad * 16;   // nx/eo row l15, col cq
  const int voa = l15 * 4;                             // A[j], bcast over quads

  // pipeline slots (static indexing only -- rule 20)
  fv4 e0[4], e1[4], e2[4], e3[4], nv[4];
  float av[4];
  fv4 agg = {0.f, 0.f, 0.f, 0.f};

#define LGRP(T, S)                                                             \
  {                                                                            \
    const int ve = voe + (T) * 4096;                                           \
    asm volatile("global_load_dwordx4 %0, %1, %2"                              \
                 : "=v"(e0[S]) : "v"(ve), "s"(ee));                            \
    asm volatile("global_load_dwordx4 %0, %1, %2 offset:16"                    \
                 : "=v"(e1[S]) : "v"(ve), "s"(ee));                            \
    asm volatile("global_load_dwordx4 %0, %1, %2 offset:128"                   \
                 : "=v"(e2[S]) : "v"(ve), "s"(ee));                            \
    asm volatile("global_load_dwordx4 %0, %1, %2 offset:144"                   \
                 : "=v"(e3[S]) : "v"(ve), "s"(ee));                            \
    const int vn = vno + (T) * 4096;                                           \
    asm volatile("global_load_dwordx4 %0, %1, %2"                              \
                 : "=v"(nv[S]) : "v"(vn), "s"(nxp));                           \
    const int va = voa + (T) * 64;                                             \
    asm volatile("global_load_dword %0, %1, %2"                                \
                 : "=v"(av[S]) : "v"(va), "s"(Ar));                            \
  }

#define WAITSB(N)                                                              \
  do {                                                                         \
    asm volatile("s_waitcnt vmcnt(" #N ")" ::: "memory");                      \
    __builtin_amdgcn_sched_barrier(0);                                         \
  } while (0)

#define COMP(T, S)                                                             \
  {                                                                            \
    const short8 af0 = cvt_frag(e0[S], e1[S]);                                 \
    const short8 af1 = cvt_frag(e2[S], e3[S]);                                 \
    fv4 acc = biasv;                         /* bias as C-in */                \
    acc = __builtin_amdgcn_mfma_f32_16x16x32_bf16(wfrag[0], af0, acc, 0,0,0);  \
    acc = __builtin_amdgcn_mfma_f32_16x16x32_bf16(wfrag[1], af1, acc, 0,0,0);  \
    fv4 rl;                                                                    \
    _Pragma("unroll") for (int r = 0; r < 4; ++r) {                            \
      rl[r] = fmaxf(acc[r], 0.0f);                                             \
      agg[r] = fmaf(av[S] * acc[r], nv[S][r], agg[r]);                         \
    }                                                                          \
    const int vo = vno + (T) * 4096;                                           \
    asm volatile("global_store_dwordx4 %0, %1, %2"                             \
                 :: "v"(vo), "v"(rl), "s"(eo));                                \
  }

  // iter t: [wait N(t)] [compute t + store t] [issue loads t+4]
#define ITER(T, S, N, PF)                                                      \
  {                                                                            \
    WAITSB(N);                                                                 \
    COMP(T, S)                                                                 \
    if (PF) LGRP((T) + 4, S)                                                   \
  }

  LGRP(0, 0) LGRP(1, 1) LGRP(2, 2) LGRP(3, 3)

  ITER(0, 0, 18, 1)
  ITER(1, 1, 19, 1)
  ITER(2, 2, 20, 1)
  ITER(3, 3, 21, 1)
  ITER(4, 0, 21, 1)
  ITER(5, 1, 21, 1)
  ITER(6, 2, 21, 1)
  ITER(7, 3, 21, 1)
  ITER(8, 0, 21, 1)
  ITER(9, 1, 21, 1)
  ITER(10, 2, 21, 1)
  ITER(11, 3, 21, 1)
  ITER(12, 0, 21, 0)
  ITER(13, 1, 15, 0)
  ITER(14, 2, 9, 0)
  ITER(15, 3, 3, 0)

#undef ITER
#undef COMP
#undef WAITSB
#undef LGRP

  // agg[r]: partial sums over this lane's rows (j = *,l15) for cols cq..cq+3.
  // Sum over the 16 l15 lanes (quad bits select col group, kept).
#pragma unroll
  for (int r = 0; r < 4; ++r) {
    agg[r] += __shfl_xor(agg[r], 1, 64);
    agg[r] += __shfl_xor(agg[r], 2, 64);
    agg[r] += __shfl_xor(agg[r], 4, 64);
    agg[r] += __shfl_xor(agg[r], 8, 64);
  }
  if (l15 == 0) {
    const fv4 rs = *(const fv4*)&rsx[(size_t)bi * CH + cq];
    fv4 out;
#pragma unroll
    for (int r = 0; r < 4; ++r) out[r] = fmaxf(agg[r], 0.0f) + rs[r];
    *(fv4*)&node_out[(size_t)bi * CH + cq] = out;
  }
}

// ---------------------------------------------------------------------------
extern "C" void kernel_launch(void* const* d_in, const int* in_sizes, int n_in,
                              void* d_out, int out_size, void* d_ws, size_t ws_size,
                              hipStream_t stream) {
  const float* A        = (const float*)d_in[0];  // [8,256,256]
  const float* emb_node = (const float*)d_in[1];  // [8,256,64]
  const float* emb_edge = (const float*)d_in[2];  // [8,256,256,64]
  const float* Wn       = (const float*)d_in[3];  // [64,64]
  const float* bn       = (const float*)d_in[4];  // [64]
  const float* Wsn      = (const float*)d_in[5];  // [64,64]
  const float* bsn      = (const float*)d_in[6];  // [64]
  const float* We       = (const float*)d_in[7];  // [64,64]
  const float* be       = (const float*)d_in[8];  // [64]

  float* node_out = (float*)d_out;                     // [2048,64]
  float* edge_out = (float*)d_out + (size_t)BN * CH;   // [2048,256,64]

  float* node_x = (float*)d_ws;                        // [2048,64] fp32
  float* rsx    = (float*)d_ws + (size_t)BN * CH;      // [2048,64] fp32

  hipLaunchKernelGGL(node_kernel, dim3(BN / 4), dim3(256), 0, stream,
                     emb_node, Wn, bn, Wsn, bsn, node_x, rsx);
  hipLaunchKernelGGL(edge_mfma_kernel, dim3(BN), dim3(256), 0, stream,
                     A, emb_edge, We, be, node_x, rsx, node_out, edge_out);
}